// Round 2
// baseline (427.031 us; speedup 1.0000x reference)
//
#include <hip/hip_runtime.h>
#include <hip/hip_bf16.h>

#define B_ 2
#define N_ 2048
#define E_ 1024
#define H_ 16
#define D_ 64
#define BH_ (B_ * H_)

typedef __attribute__((ext_vector_type(4))) float f32x4;
typedef __attribute__((ext_vector_type(8))) short bf16x8;
typedef __attribute__((ext_vector_type(4))) short s16x4;

#define MFMA(a, b, c) __builtin_amdgcn_mfma_f32_16x16x32_bf16(a, b, c, 0, 0, 0)

static __device__ __forceinline__ unsigned short f2bf(float f) {
    unsigned int u = __builtin_bit_cast(unsigned int, f);
    u += 0x7fff + ((u >> 16) & 1);   // RNE; inputs are finite
    return (unsigned short)(u >> 16);
}
static __device__ __forceinline__ float bf2f(unsigned short s) {
    unsigned int u = ((unsigned int)s) << 16;
    return __builtin_bit_cast(float, u);
}
static __device__ __forceinline__ bf16x8 cvt8(const float* __restrict__ p) {
    f32x4 a = *(const f32x4*)p;
    f32x4 b = *(const f32x4*)(p + 4);
    bf16x8 r;
    r[0] = (short)f2bf(a.x); r[1] = (short)f2bf(a.y);
    r[2] = (short)f2bf(a.z); r[3] = (short)f2bf(a.w);
    r[4] = (short)f2bf(b.x); r[5] = (short)f2bf(b.y);
    r[6] = (short)f2bf(b.z); r[7] = (short)f2bf(b.w);
    return r;
}

// ---------------------------------------------------------------------------
// Fused projections: z=0 -> qh = q@Wq^T [bh][n][d]; z=1 -> kh; z=2 -> vt
// (V transposed: [bh][d][n]).  grid (N/64, BH, 3), block 256.
// ---------------------------------------------------------------------------
__global__ __launch_bounds__(256, 4)
void proj_kernel(const float* __restrict__ q, const float* __restrict__ k,
                 const float* __restrict__ v,
                 const float* __restrict__ Wq, const float* __restrict__ Wk,
                 const float* __restrict__ Wv,
                 unsigned short* __restrict__ qh, unsigned short* __restrict__ kh,
                 unsigned short* __restrict__ vt) {
    const int z = blockIdx.z;
    const float* X = (z == 0) ? q : (z == 1) ? k : v;
    const float* W = (z == 0) ? Wq : (z == 1) ? Wk : Wv;
    unsigned short* out = (z == 0) ? qh : (z == 1) ? kh : vt;

    const int lane = threadIdx.x & 63;
    const int wave = threadIdx.x >> 6;
    const int l16  = lane & 15;
    const int quad = lane >> 4;
    const int bh = blockIdx.y;
    const int b = bh >> 4, h = bh & 15;
    const int n0 = blockIdx.x * 64;

    const int tok = n0 + wave * 16 + l16;
    const float* xrow = X + ((size_t)(b * N_ + tok)) * E_ + h * 64;
    bf16x8 xf[2];
    xf[0] = cvt8(xrow + quad * 8);
    xf[1] = cvt8(xrow + 32 + quad * 8);

    const float* Wh = W + (size_t)h * 64 * 64;
    bf16x8 wf[4][2];
#pragma unroll
    for (int t4 = 0; t4 < 4; ++t4) {
        const float* wrow = Wh + (t4 * 16 + l16) * 64;
        wf[t4][0] = cvt8(wrow + quad * 8);
        wf[t4][1] = cvt8(wrow + 32 + quad * 8);
    }

    if (z != 2) {
#pragma unroll
        for (int t4 = 0; t4 < 4; ++t4) {
            f32x4 a = {0.f, 0.f, 0.f, 0.f};
            a = MFMA(xf[0], wf[t4][0], a);
            a = MFMA(xf[1], wf[t4][1], a);
#pragma unroll
            for (int r = 0; r < 4; ++r) {
                int tk = n0 + wave * 16 + quad * 4 + r;
                out[((size_t)bh * N_ + tk) * 64 + t4 * 16 + l16] = (unsigned short)f2bf(a[r]);
            }
        }
    } else {
#pragma unroll
        for (int mi = 0; mi < 4; ++mi) {
            f32x4 a = {0.f, 0.f, 0.f, 0.f};
            a = MFMA(wf[mi][0], xf[0], a);
            a = MFMA(wf[mi][1], xf[1], a);
#pragma unroll
            for (int r = 0; r < 4; ++r) {
                int dout = mi * 16 + quad * 4 + r;
                out[((size_t)bh * 64 + dout) * N_ + (n0 + wave * 16 + l16)] =
                    (unsigned short)f2bf(a[r]);
            }
        }
    }
}

// ---------------------------------------------------------------------------
__global__ __launch_bounds__(256)
void cvt_wo_kernel(const float* __restrict__ wo, unsigned short* __restrict__ wob) {
    int idx = blockIdx.x * 256 + threadIdx.x;
    f32x4 v = *(const f32x4*)(wo + (size_t)idx * 4);
    s16x4 r = {(short)f2bf(v.x), (short)f2bf(v.y), (short)f2bf(v.z), (short)f2bf(v.w)};
    *(s16x4*)(wob + (size_t)idx * 4) = r;
}

// ---------------------------------------------------------------------------
// Flash attention, no-max softmax (scores provably small: |s|<~20 << 127).
// Q is pre-scaled by log2e/32 so P = exp2(S) directly.
// grid (N/64, BH), block 256 = 4 waves; wave = 16 q-rows.
// S^T = K*Q^T  (D: row=key, col=q);  O^T = V^T * P^T (D: row=d, col=q).
// P goes C-layout -> B-layout through a per-wave LDS tile with XOR swizzle:
//   phys_dword_col = logical_dword_col ^ ((row&7)<<2)   (conflict-free both ways)
// ---------------------------------------------------------------------------
__global__ __launch_bounds__(256, 4)
void attn_kernel(const unsigned short* __restrict__ qh,
                 const unsigned short* __restrict__ kh,
                 const unsigned short* __restrict__ vt,
                 const int* __restrict__ mask,
                 unsigned short* __restrict__ attnb) {
    __shared__ short Plds[4][16][64];   // 2 KB per wave, unpadded + swizzled

    const int lane = threadIdx.x & 63;
    const int wave = threadIdx.x >> 6;
    const int l16  = lane & 15;
    const int quad = lane >> 4;
    const int bh = blockIdx.y;
    const int b = bh >> 4, h = bh & 15;
    const int q0 = blockIdx.x * 64 + wave * 16;
    const int qrow_idx = q0 + l16;
    const int sw = (l16 & 7) << 2;           // XOR swizzle for this lane's P row
    short* pbase = &Plds[wave][0][0] + l16 * 64;

    // Q fragment (B-operand: lane=q col, quad*8 = d offset), scaled by
    // log2e/32 (so exp2 needs no multiply), zeroed for masked query rows.
    const int mk = mask[b * N_ + qrow_idx];
    const float qscale = 1.44269504f * 0.03125f;
    bf16x8 qf[2];
    {
        const unsigned short* qrow = qh + ((size_t)bh * N_ + qrow_idx) * 64;
#pragma unroll
        for (int c = 0; c < 2; ++c) {
            bf16x8 raw = *(const bf16x8*)(qrow + c * 32 + quad * 8);
            bf16x8 t;
#pragma unroll
            for (int j = 0; j < 8; ++j) {
                float f = bf2f((unsigned short)raw[j]) * qscale;
                t[j] = mk ? (short)f2bf(f) : (short)0;
            }
            qf[c] = t;
        }
    }

    float lI = 0.f;
    f32x4 o[4];
#pragma unroll
    for (int mi = 0; mi < 4; ++mi) o[mi] = (f32x4){0.f, 0.f, 0.f, 0.f};

    for (int kt = 0; kt < N_ / 64; ++kt) {
        const int k0 = kt * 64;

        // K fragments (A-operand: lane=key row, quad*8 = d offset)
        bf16x8 ka[4][2];
#pragma unroll
        for (int t4 = 0; t4 < 4; ++t4) {
            const unsigned short* krow = kh + ((size_t)bh * N_ + k0 + t4 * 16 + l16) * 64;
            ka[t4][0] = *(const bf16x8*)(krow + quad * 8);
            ka[t4][1] = *(const bf16x8*)(krow + 32 + quad * 8);
        }

        // S^T tile: s[t4][r] is key (t4*16+quad*4+r), q-col l16
        f32x4 s[4];
#pragma unroll
        for (int t4 = 0; t4 < 4; ++t4) {
            f32x4 z = {0.f, 0.f, 0.f, 0.f};
            z = MFMA(ka[t4][0], qf[0], z);
            z = MFMA(ka[t4][1], qf[1], z);
            s[t4] = z;
        }

        // P = exp2(S), accumulate row sum, pack to bf16 into swizzled LDS
        float rsum = 0.f;
#pragma unroll
        for (int t4 = 0; t4 < 4; ++t4) {
            f32x4 p;
#pragma unroll
            for (int r = 0; r < 4; ++r) {
                p[r] = __builtin_amdgcn_exp2f(s[t4][r]);
                rsum += p[r];
            }
            s16x4 pk = {(short)f2bf(p.x), (short)f2bf(p.y),
                        (short)f2bf(p.z), (short)f2bf(p.w)};
            // logical dword col = t4*8 + quad*2 ; row = l16
            *(s16x4*)(pbase + (((t4 * 8 + quad * 2) ^ sw) << 1)) = pk;
        }
        rsum += __shfl_xor(rsum, 16);
        rsum += __shfl_xor(rsum, 32);
        lI += rsum;

        asm volatile("s_waitcnt lgkmcnt(0)" ::: "memory");

        // P as B-operand: lane=q col l16, keys quad*8.. (+32)
        bf16x8 pb0 = *(const bf16x8*)(pbase + (((quad * 4) ^ sw) << 1));
        bf16x8 pb1 = *(const bf16x8*)(pbase + (((16 + quad * 4) ^ sw) << 1));

#pragma unroll
        for (int mi = 0; mi < 4; ++mi) {
            const unsigned short* vrow = vt + ((size_t)bh * 64 + mi * 16 + l16) * N_ + k0;
            bf16x8 va0 = *(const bf16x8*)(vrow + quad * 8);
            bf16x8 va1 = *(const bf16x8*)(vrow + 32 + quad * 8);
            o[mi] = MFMA(va0, pb0, o[mi]);
            o[mi] = MFMA(va1, pb1, o[mi]);
        }
    }

    const float inv = 1.0f / lI;
#pragma unroll
    for (int mi = 0; mi < 4; ++mi) {
        f32x4 ov = o[mi];
        s16x4 pk = {(short)f2bf(ov.x * inv), (short)f2bf(ov.y * inv),
                    (short)f2bf(ov.z * inv), (short)f2bf(ov.w * inv)};
        int d0 = mi * 16 + quad * 4;
        *(s16x4*)(attnb + ((size_t)(b * N_ + qrow_idx)) * E_ + h * 64 + d0) = pk;
    }
}

// ---------------------------------------------------------------------------
// out = attn(bf16) @ Wo^T(bf16), fp32 out. grid (B*N/64, E/64), block 256.
// Wave: 16 token rows x 64 out-cols.
// ---------------------------------------------------------------------------
__global__ __launch_bounds__(256, 4)
void out_gemm_kernel(const unsigned short* __restrict__ attnb,
                     const unsigned short* __restrict__ wob,
                     float* __restrict__ out) {
    const int lane = threadIdx.x & 63;
    const int wave = threadIdx.x >> 6;
    const int l16  = lane & 15;
    const int quad = lane >> 4;
    const int t0 = blockIdx.x * 64 + wave * 16;
    const int c0 = blockIdx.y * 64;

    f32x4 acc[4];
#pragma unroll
    for (int t4 = 0; t4 < 4; ++t4) acc[t4] = (f32x4){0.f, 0.f, 0.f, 0.f};

    for (int kc = 0; kc < E_ / 32; ++kc) {
        bf16x8 a = *(const bf16x8*)(attnb + (size_t)(t0 + l16) * E_ + kc * 32 + quad * 8);
        bf16x8 bb[4];
#pragma unroll
        for (int t4 = 0; t4 < 4; ++t4)
            bb[t4] = *(const bf16x8*)(wob + (size_t)(c0 + t4 * 16 + l16) * E_ +
                                      kc * 32 + quad * 8);
#pragma unroll
        for (int t4 = 0; t4 < 4; ++t4)
            acc[t4] = MFMA(a, bb[t4], acc[t4]);
    }

#pragma unroll
    for (int t4 = 0; t4 < 4; ++t4)
#pragma unroll
        for (int r = 0; r < 4; ++r)
            out[(size_t)(t0 + quad * 4 + r) * E_ + c0 + t4 * 16 + l16] = acc[t4][r];
}

// ---------------------------------------------------------------------------
extern "C" void kernel_launch(void* const* d_in, const int* in_sizes, int n_in,
                              void* d_out, int out_size, void* d_ws, size_t ws_size,
                              hipStream_t stream) {
    const float* q    = (const float*)d_in[0];
    const float* k    = (const float*)d_in[1];
    const float* v    = (const float*)d_in[2];
    const int*   mask = (const int*)d_in[3];
    const float* Wq   = (const float*)d_in[4];
    const float* Wk   = (const float*)d_in[5];
    const float* Wv   = (const float*)d_in[6];
    const float* Wo   = (const float*)d_in[7];
    float* out = (float*)d_out;

    char* ws = (char*)d_ws;
    unsigned short* qh    = (unsigned short*)(ws);
    unsigned short* kh    = (unsigned short*)(ws + (size_t)8 * 1024 * 1024);
    unsigned short* vt    = (unsigned short*)(ws + (size_t)16 * 1024 * 1024);
    unsigned short* attnb = (unsigned short*)(ws + (size_t)24 * 1024 * 1024);
    // wob aliases qh's region: cvt_wo runs AFTER attn is done reading qh.
    unsigned short* wob   = (unsigned short*)(ws);

    dim3 blk(256);
    proj_kernel<<<dim3(N_ / 64, BH_, 3), blk, 0, stream>>>(q, k, v, Wq, Wk, Wv, qh, kh, vt);
    attn_kernel<<<dim3(N_ / 64, BH_), blk, 0, stream>>>(qh, kh, vt, mask, attnb);
    cvt_wo_kernel<<<dim3(E_ * E_ / 1024), blk, 0, stream>>>(Wo, wob);
    out_gemm_kernel<<<dim3(B_ * N_ / 64, E_ / 64), blk, 0, stream>>>(attnb, wob, out);
}

// Round 3
// 403.258 us; speedup vs baseline: 1.0590x; 1.0590x over previous
//
#include <hip/hip_runtime.h>
#include <hip/hip_bf16.h>

#define B_ 2
#define N_ 2048
#define E_ 1024
#define H_ 16
#define D_ 64
#define BH_ (B_ * H_)

typedef __attribute__((ext_vector_type(4))) float f32x4;
typedef __attribute__((ext_vector_type(8))) short bf16x8;
typedef __attribute__((ext_vector_type(4))) short s16x4;
typedef __attribute__((ext_vector_type(4))) int i32x4;

#define MFMA(a, b, c) __builtin_amdgcn_mfma_f32_16x16x32_bf16(a, b, c, 0, 0, 0)

static __device__ __forceinline__ unsigned short f2bf(float f) {
    unsigned int u = __builtin_bit_cast(unsigned int, f);
    u += 0x7fff + ((u >> 16) & 1);   // RNE; inputs are finite
    return (unsigned short)(u >> 16);
}
static __device__ __forceinline__ float bf2f(unsigned short s) {
    unsigned int u = ((unsigned int)s) << 16;
    return __builtin_bit_cast(float, u);
}
static __device__ __forceinline__ int pack2bf(float lo, float hi) {
    return (int)f2bf(lo) | ((int)f2bf(hi) << 16);
}
static __device__ __forceinline__ bf16x8 cvt8(const float* __restrict__ p) {
    f32x4 a = *(const f32x4*)p;
    f32x4 b = *(const f32x4*)(p + 4);
    bf16x8 r;
    r[0] = (short)f2bf(a.x); r[1] = (short)f2bf(a.y);
    r[2] = (short)f2bf(a.z); r[3] = (short)f2bf(a.w);
    r[4] = (short)f2bf(b.x); r[5] = (short)f2bf(b.y);
    r[6] = (short)f2bf(b.z); r[7] = (short)f2bf(b.w);
    return r;
}

// ---------------------------------------------------------------------------
// Fused projections: z=0 -> qh = q@Wq^T [bh][n][d]; z=1 -> kh; z=2 -> vt
// (V transposed: [bh][d][n]).  grid (N/64, BH, 3), block 256.
// ---------------------------------------------------------------------------
__global__ __launch_bounds__(256, 4)
void proj_kernel(const float* __restrict__ q, const float* __restrict__ k,
                 const float* __restrict__ v,
                 const float* __restrict__ Wq, const float* __restrict__ Wk,
                 const float* __restrict__ Wv,
                 unsigned short* __restrict__ qh, unsigned short* __restrict__ kh,
                 unsigned short* __restrict__ vt) {
    const int z = blockIdx.z;
    const float* X = (z == 0) ? q : (z == 1) ? k : v;
    const float* W = (z == 0) ? Wq : (z == 1) ? Wk : Wv;
    unsigned short* out = (z == 0) ? qh : (z == 1) ? kh : vt;

    const int lane = threadIdx.x & 63;
    const int wave = threadIdx.x >> 6;
    const int l16  = lane & 15;
    const int quad = lane >> 4;
    const int bh = blockIdx.y;
    const int b = bh >> 4, h = bh & 15;
    const int n0 = blockIdx.x * 64;

    const int tok = n0 + wave * 16 + l16;
    const float* xrow = X + ((size_t)(b * N_ + tok)) * E_ + h * 64;
    bf16x8 xf[2];
    xf[0] = cvt8(xrow + quad * 8);
    xf[1] = cvt8(xrow + 32 + quad * 8);

    const float* Wh = W + (size_t)h * 64 * 64;
    bf16x8 wf[4][2];
#pragma unroll
    for (int t4 = 0; t4 < 4; ++t4) {
        const float* wrow = Wh + (t4 * 16 + l16) * 64;
        wf[t4][0] = cvt8(wrow + quad * 8);
        wf[t4][1] = cvt8(wrow + 32 + quad * 8);
    }

    if (z != 2) {
#pragma unroll
        for (int t4 = 0; t4 < 4; ++t4) {
            f32x4 a = {0.f, 0.f, 0.f, 0.f};
            a = MFMA(xf[0], wf[t4][0], a);
            a = MFMA(xf[1], wf[t4][1], a);
#pragma unroll
            for (int r = 0; r < 4; ++r) {
                int tk = n0 + wave * 16 + quad * 4 + r;
                out[((size_t)bh * N_ + tk) * 64 + t4 * 16 + l16] = (unsigned short)f2bf(a[r]);
            }
        }
    } else {
#pragma unroll
        for (int mi = 0; mi < 4; ++mi) {
            f32x4 a = {0.f, 0.f, 0.f, 0.f};
            a = MFMA(wf[mi][0], xf[0], a);
            a = MFMA(wf[mi][1], xf[1], a);
#pragma unroll
            for (int r = 0; r < 4; ++r) {
                int dout = mi * 16 + quad * 4 + r;
                out[((size_t)bh * 64 + dout) * N_ + (n0 + wave * 16 + l16)] =
                    (unsigned short)f2bf(a[r]);
            }
        }
    }
}

// ---------------------------------------------------------------------------
__global__ __launch_bounds__(256)
void cvt_wo_kernel(const float* __restrict__ wo, unsigned short* __restrict__ wob) {
    int idx = blockIdx.x * 256 + threadIdx.x;
    f32x4 v = *(const f32x4*)(wo + (size_t)idx * 4);
    s16x4 r = {(short)f2bf(v.x), (short)f2bf(v.y), (short)f2bf(v.z), (short)f2bf(v.w)};
    *(s16x4*)(wob + (size_t)idx * 4) = r;
}

// ---------------------------------------------------------------------------
// Flash attention, no-max softmax (|s| <= ~20 << fp32 exp2 range).
// Q pre-scaled by log2e/32 so P = exp2(S).  NO LDS, NO barriers:
// the P C-layout -> B-layout transform is a pure cross-lane permute among
// the 4 lanes sharing a q-column: 16 __shfl + 8 cndmask per k-tile.
// grid (N/64, BH), block 256 = 4 waves; wave = 16 q-rows.
// S^T = K*Q^T  (D: row=key, col=q);  O^T = V^T * P^T (D: row=d, col=q).
// ---------------------------------------------------------------------------
__global__ __launch_bounds__(256, 4)
void attn_kernel(const unsigned short* __restrict__ qh,
                 const unsigned short* __restrict__ kh,
                 const unsigned short* __restrict__ vt,
                 const int* __restrict__ mask,
                 unsigned short* __restrict__ attnb) {
    const int lane = threadIdx.x & 63;
    const int l16  = lane & 15;
    const int quad = lane >> 4;
    const int bh = blockIdx.y;
    const int b = bh >> 4, h = bh & 15;
    const int wave = threadIdx.x >> 6;
    const int q0 = blockIdx.x * 64 + wave * 16;
    const int qrow_idx = q0 + l16;

    // cross-lane transform source lanes (constant per lane)
    const int srcA = (((quad * 2) & 3) << 4) + l16;      // keys j=0..3 provider
    const int srcB = (((quad * 2 + 1) & 3) << 4) + l16;  // keys j=4..7 provider
    const bool hiSel = (quad >= 2);

    // Q fragment (B-operand), scaled by log2e/32, zeroed for masked rows.
    const int mk = mask[b * N_ + qrow_idx];
    const float qscale = 1.44269504f * 0.03125f;
    bf16x8 qf[2];
    {
        const unsigned short* qrow = qh + ((size_t)bh * N_ + qrow_idx) * 64;
#pragma unroll
        for (int c = 0; c < 2; ++c) {
            bf16x8 raw = *(const bf16x8*)(qrow + c * 32 + quad * 8);
            bf16x8 t;
#pragma unroll
            for (int j = 0; j < 8; ++j) {
                float f = bf2f((unsigned short)raw[j]) * qscale;
                t[j] = mk ? (short)f2bf(f) : (short)0;
            }
            qf[c] = t;
        }
    }

    float lI = 0.f;
    f32x4 o[4];
#pragma unroll
    for (int mi = 0; mi < 4; ++mi) o[mi] = (f32x4){0.f, 0.f, 0.f, 0.f};

    const unsigned short* kbase = kh + (size_t)bh * N_ * 64;
    const unsigned short* vbase = vt + (size_t)bh * 64 * N_;

    for (int kt = 0; kt < N_ / 64; ++kt) {
        const int k0 = kt * 64;

        // V fragments for this tile — independent of P, issue first
        bf16x8 va[4][2];
#pragma unroll
        for (int mi = 0; mi < 4; ++mi) {
            const unsigned short* vrow = vbase + (size_t)(mi * 16 + l16) * N_ + k0;
            va[mi][0] = *(const bf16x8*)(vrow + quad * 8);
            va[mi][1] = *(const bf16x8*)(vrow + 32 + quad * 8);
        }

        // K fragments (A-operand)
        bf16x8 ka[4][2];
#pragma unroll
        for (int t4 = 0; t4 < 4; ++t4) {
            const unsigned short* krow = kbase + (size_t)(k0 + t4 * 16 + l16) * 64;
            ka[t4][0] = *(const bf16x8*)(krow + quad * 8);
            ka[t4][1] = *(const bf16x8*)(krow + 32 + quad * 8);
        }

        // S^T tile: s[t4][r] = score(key = k0+t4*16+quad*4+r, q-col = l16)
        f32x4 s[4];
#pragma unroll
        for (int t4 = 0; t4 < 4; ++t4) {
            f32x4 z = {0.f, 0.f, 0.f, 0.f};
            z = MFMA(ka[t4][0], qf[0], z);
            z = MFMA(ka[t4][1], qf[1], z);
            s[t4] = z;
        }

        // P = exp2(S); pack each t4's 4 keys into 2 dwords (bf16 pairs)
        float rsum = 0.f;
        int pk[4][2];
#pragma unroll
        for (int t4 = 0; t4 < 4; ++t4) {
            f32x4 p;
#pragma unroll
            for (int r = 0; r < 4; ++r) {
                p[r] = __builtin_amdgcn_exp2f(s[t4][r]);
                rsum += p[r];
            }
            pk[t4][0] = pack2bf(p.x, p.y);
            pk[t4][1] = pack2bf(p.z, p.w);
        }
        rsum += __shfl_xor(rsum, 16);
        rsum += __shfl_xor(rsum, 32);
        lI += rsum;

        // Transform to B-operand layout: lane (quad,l16) needs keys
        // quad*8+{0..7} (pb0) and 32+quad*8+{0..7} (pb1), col l16.
        i32x4 w0, w1;
#pragma unroll
        for (int d = 0; d < 2; ++d) {
            int a0 = __shfl(pk[0][d], srcA), a1 = __shfl(pk[1][d], srcA);
            int b0 = __shfl(pk[0][d], srcB), b1 = __shfl(pk[1][d], srcB);
            w0[d]     = hiSel ? a1 : a0;
            w0[2 + d] = hiSel ? b1 : b0;
            int c0 = __shfl(pk[2][d], srcA), c1 = __shfl(pk[3][d], srcA);
            int e0 = __shfl(pk[2][d], srcB), e1 = __shfl(pk[3][d], srcB);
            w1[d]     = hiSel ? c1 : c0;
            w1[2 + d] = hiSel ? e1 : e0;
        }
        bf16x8 pb0 = __builtin_bit_cast(bf16x8, w0);
        bf16x8 pb1 = __builtin_bit_cast(bf16x8, w1);

#pragma unroll
        for (int mi = 0; mi < 4; ++mi) {
            o[mi] = MFMA(va[mi][0], pb0, o[mi]);
            o[mi] = MFMA(va[mi][1], pb1, o[mi]);
        }
    }

    const float inv = 1.0f / lI;
#pragma unroll
    for (int mi = 0; mi < 4; ++mi) {
        f32x4 ov = o[mi];
        s16x4 pkk = {(short)f2bf(ov.x * inv), (short)f2bf(ov.y * inv),
                     (short)f2bf(ov.z * inv), (short)f2bf(ov.w * inv)};
        int d0 = mi * 16 + quad * 4;
        *(s16x4*)(attnb + ((size_t)(b * N_ + qrow_idx)) * E_ + h * 64 + d0) = pkk;
    }
}

// ---------------------------------------------------------------------------
// out = attn(bf16) @ Wo^T(bf16), fp32 out. grid (B*N/128, E/64), block 256.
// Wave: 32 token rows (2 m-tiles) x 64 out-cols (4 n-tiles), K-unroll 2.
// ---------------------------------------------------------------------------
__global__ __launch_bounds__(256, 4)
void out_gemm_kernel(const unsigned short* __restrict__ attnb,
                     const unsigned short* __restrict__ wob,
                     float* __restrict__ out) {
    const int lane = threadIdx.x & 63;
    const int wave = threadIdx.x >> 6;
    const int l16  = lane & 15;
    const int quad = lane >> 4;
    const int t0 = blockIdx.x * 128 + wave * 32;
    const int c0 = blockIdx.y * 64;

    f32x4 acc[2][4];
#pragma unroll
    for (int mi = 0; mi < 2; ++mi)
#pragma unroll
        for (int t4 = 0; t4 < 4; ++t4) acc[mi][t4] = (f32x4){0.f, 0.f, 0.f, 0.f};

#pragma unroll 2
    for (int kc = 0; kc < E_ / 32; ++kc) {
        bf16x8 a[2], bb[4];
#pragma unroll
        for (int mi = 0; mi < 2; ++mi)
            a[mi] = *(const bf16x8*)(attnb + (size_t)(t0 + mi * 16 + l16) * E_ +
                                     kc * 32 + quad * 8);
#pragma unroll
        for (int t4 = 0; t4 < 4; ++t4)
            bb[t4] = *(const bf16x8*)(wob + (size_t)(c0 + t4 * 16 + l16) * E_ +
                                      kc * 32 + quad * 8);
#pragma unroll
        for (int mi = 0; mi < 2; ++mi)
#pragma unroll
            for (int t4 = 0; t4 < 4; ++t4)
                acc[mi][t4] = MFMA(a[mi], bb[t4], acc[mi][t4]);
    }

#pragma unroll
    for (int mi = 0; mi < 2; ++mi)
#pragma unroll
        for (int t4 = 0; t4 < 4; ++t4)
#pragma unroll
            for (int r = 0; r < 4; ++r)
                out[(size_t)(t0 + mi * 16 + quad * 4 + r) * E_ + c0 + t4 * 16 + l16] =
                    acc[mi][t4][r];
}

// ---------------------------------------------------------------------------
extern "C" void kernel_launch(void* const* d_in, const int* in_sizes, int n_in,
                              void* d_out, int out_size, void* d_ws, size_t ws_size,
                              hipStream_t stream) {
    const float* q    = (const float*)d_in[0];
    const float* k    = (const float*)d_in[1];
    const float* v    = (const float*)d_in[2];
    const int*   mask = (const int*)d_in[3];
    const float* Wq   = (const float*)d_in[4];
    const float* Wk   = (const float*)d_in[5];
    const float* Wv   = (const float*)d_in[6];
    const float* Wo   = (const float*)d_in[7];
    float* out = (float*)d_out;

    char* ws = (char*)d_ws;
    unsigned short* qh    = (unsigned short*)(ws);
    unsigned short* kh    = (unsigned short*)(ws + (size_t)8 * 1024 * 1024);
    unsigned short* vt    = (unsigned short*)(ws + (size_t)16 * 1024 * 1024);
    unsigned short* attnb = (unsigned short*)(ws + (size_t)24 * 1024 * 1024);
    // wob aliases qh's region: cvt_wo runs AFTER attn is done reading qh.
    unsigned short* wob   = (unsigned short*)(ws);

    dim3 blk(256);
    proj_kernel<<<dim3(N_ / 64, BH_, 3), blk, 0, stream>>>(q, k, v, Wq, Wk, Wv, qh, kh, vt);
    attn_kernel<<<dim3(N_ / 64, BH_), blk, 0, stream>>>(qh, kh, vt, mask, attnb);
    cvt_wo_kernel<<<dim3(E_ * E_ / 1024), blk, 0, stream>>>(Wo, wob);
    out_gemm_kernel<<<dim3(B_ * N_ / 128, E_ / 64), blk, 0, stream>>>(attnb, wob, out);
}

// Round 4
// 241.806 us; speedup vs baseline: 1.7660x; 1.6677x over previous
//
#include <hip/hip_runtime.h>
#include <hip/hip_bf16.h>

#define B_ 2
#define N_ 2048
#define E_ 1024
#define H_ 16
#define D_ 64
#define BH_ (B_ * H_)

typedef __attribute__((ext_vector_type(4))) float f32x4;
typedef __attribute__((ext_vector_type(8))) short bf16x8;
typedef __attribute__((ext_vector_type(4))) short s16x4;
typedef __attribute__((ext_vector_type(4))) int i32x4;

#define MFMA(a, b, c) __builtin_amdgcn_mfma_f32_16x16x32_bf16(a, b, c, 0, 0, 0)

static __device__ __forceinline__ unsigned short f2bf(float f) {
    unsigned int u = __builtin_bit_cast(unsigned int, f);
    u += 0x7fff + ((u >> 16) & 1);   // RNE; inputs are finite
    return (unsigned short)(u >> 16);
}
static __device__ __forceinline__ float bf2f(unsigned short s) {
    unsigned int u = ((unsigned int)s) << 16;
    return __builtin_bit_cast(float, u);
}
static __device__ __forceinline__ int pack2bf(float lo, float hi) {
    return (int)f2bf(lo) | ((int)f2bf(hi) << 16);
}
static __device__ __forceinline__ bf16x8 cvt8(const float* __restrict__ p) {
    f32x4 a = *(const f32x4*)p;
    f32x4 b = *(const f32x4*)(p + 4);
    bf16x8 r;
    r[0] = (short)f2bf(a.x); r[1] = (short)f2bf(a.y);
    r[2] = (short)f2bf(a.z); r[3] = (short)f2bf(a.w);
    r[4] = (short)f2bf(b.x); r[5] = (short)f2bf(b.y);
    r[6] = (short)f2bf(b.z); r[7] = (short)f2bf(b.w);
    return r;
}

// ---------------------------------------------------------------------------
// Fused projections: z=0 -> qh = q@Wq^T [bh][n][d]; z=1 -> kh; z=2 -> vt
// (V transposed: [bh][d][n]).  grid (N/64, BH, 3), block 256.
// ---------------------------------------------------------------------------
__global__ __launch_bounds__(256, 4)
void proj_kernel(const float* __restrict__ q, const float* __restrict__ k,
                 const float* __restrict__ v,
                 const float* __restrict__ Wq, const float* __restrict__ Wk,
                 const float* __restrict__ Wv,
                 unsigned short* __restrict__ qh, unsigned short* __restrict__ kh,
                 unsigned short* __restrict__ vt) {
    const int z = blockIdx.z;
    const float* X = (z == 0) ? q : (z == 1) ? k : v;
    const float* W = (z == 0) ? Wq : (z == 1) ? Wk : Wv;
    unsigned short* out = (z == 0) ? qh : (z == 1) ? kh : vt;

    const int lane = threadIdx.x & 63;
    const int wave = threadIdx.x >> 6;
    const int l16  = lane & 15;
    const int quad = lane >> 4;
    const int bh = blockIdx.y;
    const int b = bh >> 4, h = bh & 15;
    const int n0 = blockIdx.x * 64;

    const int tok = n0 + wave * 16 + l16;
    const float* xrow = X + ((size_t)(b * N_ + tok)) * E_ + h * 64;
    bf16x8 xf[2];
    xf[0] = cvt8(xrow + quad * 8);
    xf[1] = cvt8(xrow + 32 + quad * 8);

    const float* Wh = W + (size_t)h * 64 * 64;
    bf16x8 wf[4][2];
#pragma unroll
    for (int t4 = 0; t4 < 4; ++t4) {
        const float* wrow = Wh + (t4 * 16 + l16) * 64;
        wf[t4][0] = cvt8(wrow + quad * 8);
        wf[t4][1] = cvt8(wrow + 32 + quad * 8);
    }

    if (z != 2) {
#pragma unroll
        for (int t4 = 0; t4 < 4; ++t4) {
            f32x4 a = {0.f, 0.f, 0.f, 0.f};
            a = MFMA(xf[0], wf[t4][0], a);
            a = MFMA(xf[1], wf[t4][1], a);
#pragma unroll
            for (int r = 0; r < 4; ++r) {
                int tk = n0 + wave * 16 + quad * 4 + r;
                out[((size_t)bh * N_ + tk) * 64 + t4 * 16 + l16] = (unsigned short)f2bf(a[r]);
            }
        }
    } else {
#pragma unroll
        for (int mi = 0; mi < 4; ++mi) {
            f32x4 a = {0.f, 0.f, 0.f, 0.f};
            a = MFMA(wf[mi][0], xf[0], a);
            a = MFMA(wf[mi][1], xf[1], a);
#pragma unroll
            for (int r = 0; r < 4; ++r) {
                int dout = mi * 16 + quad * 4 + r;
                out[((size_t)bh * 64 + dout) * N_ + (n0 + wave * 16 + l16)] =
                    (unsigned short)f2bf(a[r]);
            }
        }
    }
}

// ---------------------------------------------------------------------------
__global__ __launch_bounds__(256)
void cvt_wo_kernel(const float* __restrict__ wo, unsigned short* __restrict__ wob) {
    int idx = blockIdx.x * 256 + threadIdx.x;
    f32x4 v = *(const f32x4*)(wo + (size_t)idx * 4);
    s16x4 r = {(short)f2bf(v.x), (short)f2bf(v.y), (short)f2bf(v.z), (short)f2bf(v.w)};
    *(s16x4*)(wob + (size_t)idx * 4) = r;
}

// ---------------------------------------------------------------------------
// Flash attention v4: block = 4 waves x 32 q-rows = 128 q.  K/V tiles staged
// to LDS once per block (double-buffered, padded rows: 64+8 elems -> <=2-way
// bank access = free).  XCD-aware block swizzle: dispatch-linear id % 8 picks
// the XCD (round-robin heuristic), so each XCD touches only 4 heads ->
// K/V working set 2 MB < 4 MB L2 (was 16 MB -> L2 thrash -> L3-BW-bound).
// No-max softmax (|s| small), Q pre-scaled by log2e/32, P = exp2(S).
// P transform C-layout -> B-layout via cross-lane shuffles (no barriers).
// ---------------------------------------------------------------------------
__global__ __launch_bounds__(256, 2)
void attn_kernel(const unsigned short* __restrict__ qh,
                 const unsigned short* __restrict__ kh,
                 const unsigned short* __restrict__ vt,
                 const int* __restrict__ mask,
                 unsigned short* __restrict__ attnb) {
    __shared__ short Kb[2][64][72];   // 18 KB
    __shared__ short Vb[2][64][72];   // 18 KB

    const int tid  = threadIdx.x;
    const int lane = tid & 63;
    const int wave = tid >> 6;
    const int l16  = lane & 15;
    const int quad = lane >> 4;

    // XCD swizzle: flat dispatch id -> (qblk, bh) with bh grouped by id%8
    const int flat = blockIdx.y * gridDim.x + blockIdx.x;   // 0..511
    const int qblk = flat >> 5;                              // 0..15
    const int rem  = flat & 31;
    const int bh   = ((rem & 7) << 2) | (rem >> 3);          // 4*(id%8)+..
    const int b = bh >> 4, h = bh & 15;
    const int q0 = qblk * 128 + wave * 32;

    const unsigned short* kbase = kh + (size_t)bh * N_ * 64;
    const unsigned short* vbase = vt + (size_t)bh * 64 * N_;

    // staging chunk ids (8 elems = 16 B per chunk; 512 chunks per 8 KB tile)
    const int c0i = tid;         // pass 0
    const int c1i = tid + 256;   // pass 1

    // cross-lane P-transform constants
    const int srcA = (((quad * 2) & 3) << 4) + l16;
    const int srcB = (((quad * 2 + 1) & 3) << 4) + l16;
    const bool hiSel = (quad >= 2);

    // Q fragments (B-operand), scaled by log2e/32, zeroed for masked rows
    const float qscale = 1.44269504f * 0.03125f;
    bf16x8 qf[2][2];
#pragma unroll
    for (int qi = 0; qi < 2; ++qi) {
        const int qrow_idx = q0 + qi * 16 + l16;
        const int mk = mask[b * N_ + qrow_idx];
        const unsigned short* qrow = qh + ((size_t)bh * N_ + qrow_idx) * 64;
#pragma unroll
        for (int c = 0; c < 2; ++c) {
            bf16x8 raw = *(const bf16x8*)(qrow + c * 32 + quad * 8);
            bf16x8 t;
#pragma unroll
            for (int j = 0; j < 8; ++j) {
                float f = bf2f((unsigned short)raw[j]) * qscale;
                t[j] = mk ? (short)f2bf(f) : (short)0;
            }
            qf[qi][c] = t;
        }
    }

    float lI[2] = {0.f, 0.f};
    f32x4 o[4][2];
#pragma unroll
    for (int mi = 0; mi < 4; ++mi)
#pragma unroll
        for (int qi = 0; qi < 2; ++qi) o[mi][qi] = (f32x4){0.f, 0.f, 0.f, 0.f};

    // stage tile 0
    bf16x8 gK0, gK1, gV0, gV1;
    gK0 = *(const bf16x8*)(kbase + c0i * 8);
    gK1 = *(const bf16x8*)(kbase + c1i * 8);
    gV0 = *(const bf16x8*)(vbase + (size_t)(c0i >> 3) * N_ + (c0i & 7) * 8);
    gV1 = *(const bf16x8*)(vbase + (size_t)(c1i >> 3) * N_ + (c1i & 7) * 8);
    *(bf16x8*)(&Kb[0][c0i >> 3][(c0i & 7) * 8]) = gK0;
    *(bf16x8*)(&Kb[0][c1i >> 3][(c1i & 7) * 8]) = gK1;
    *(bf16x8*)(&Vb[0][c0i >> 3][(c0i & 7) * 8]) = gV0;
    *(bf16x8*)(&Vb[0][c1i >> 3][(c1i & 7) * 8]) = gV1;
    __syncthreads();

    for (int kt = 0; kt < N_ / 64; ++kt) {
        const int cur = kt & 1;

        // prefetch next tile into registers (overlaps with compute)
        if (kt + 1 < N_ / 64) {
            const int k0n = (kt + 1) * 64;
            gK0 = *(const bf16x8*)(kbase + (size_t)k0n * 64 + c0i * 8);
            gK1 = *(const bf16x8*)(kbase + (size_t)k0n * 64 + c1i * 8);
            gV0 = *(const bf16x8*)(vbase + (size_t)(c0i >> 3) * N_ + k0n + (c0i & 7) * 8);
            gV1 = *(const bf16x8*)(vbase + (size_t)(c1i >> 3) * N_ + k0n + (c1i & 7) * 8);
        }

        // K fragments from LDS (A-operand: row = key, cols = d)
        bf16x8 ka[4][2];
#pragma unroll
        for (int t4 = 0; t4 < 4; ++t4) {
            ka[t4][0] = *(const bf16x8*)(&Kb[cur][t4 * 16 + l16][quad * 8]);
            ka[t4][1] = *(const bf16x8*)(&Kb[cur][t4 * 16 + l16][32 + quad * 8]);
        }

        // S^T tiles
        f32x4 s[2][4];
#pragma unroll
        for (int qi = 0; qi < 2; ++qi)
#pragma unroll
            for (int t4 = 0; t4 < 4; ++t4) {
                f32x4 z = {0.f, 0.f, 0.f, 0.f};
                z = MFMA(ka[t4][0], qf[qi][0], z);
                z = MFMA(ka[t4][1], qf[qi][1], z);
                s[qi][t4] = z;
            }

        // V fragments from LDS (A-operand: row = d, cols = key)
        bf16x8 va[4][2];
#pragma unroll
        for (int mi = 0; mi < 4; ++mi) {
            va[mi][0] = *(const bf16x8*)(&Vb[cur][mi * 16 + l16][quad * 8]);
            va[mi][1] = *(const bf16x8*)(&Vb[cur][mi * 16 + l16][32 + quad * 8]);
        }

        // softmax + P transform + PV, per qi
#pragma unroll
        for (int qi = 0; qi < 2; ++qi) {
            float rsum = 0.f;
            int pk[4][2];
#pragma unroll
            for (int t4 = 0; t4 < 4; ++t4) {
                f32x4 p;
#pragma unroll
                for (int r = 0; r < 4; ++r) {
                    p[r] = __builtin_amdgcn_exp2f(s[qi][t4][r]);
                    rsum += p[r];
                }
                pk[t4][0] = pack2bf(p.x, p.y);
                pk[t4][1] = pack2bf(p.z, p.w);
            }
            rsum += __shfl_xor(rsum, 16);
            rsum += __shfl_xor(rsum, 32);
            lI[qi] += rsum;

            i32x4 w0, w1;
#pragma unroll
            for (int d = 0; d < 2; ++d) {
                int a0 = __shfl(pk[0][d], srcA), a1 = __shfl(pk[1][d], srcA);
                int b0 = __shfl(pk[0][d], srcB), b1 = __shfl(pk[1][d], srcB);
                w0[d]     = hiSel ? a1 : a0;
                w0[2 + d] = hiSel ? b1 : b0;
                int c0 = __shfl(pk[2][d], srcA), c1 = __shfl(pk[3][d], srcA);
                int e0 = __shfl(pk[2][d], srcB), e1 = __shfl(pk[3][d], srcB);
                w1[d]     = hiSel ? c1 : c0;
                w1[2 + d] = hiSel ? e1 : e0;
            }
            bf16x8 pb0 = __builtin_bit_cast(bf16x8, w0);
            bf16x8 pb1 = __builtin_bit_cast(bf16x8, w1);

#pragma unroll
            for (int mi = 0; mi < 4; ++mi) {
                o[mi][qi] = MFMA(va[mi][0], pb0, o[mi][qi]);
                o[mi][qi] = MFMA(va[mi][1], pb1, o[mi][qi]);
            }
        }

        // write next tile into the other buffer, then barrier
        if (kt + 1 < N_ / 64) {
            const int nxt = cur ^ 1;
            *(bf16x8*)(&Kb[nxt][c0i >> 3][(c0i & 7) * 8]) = gK0;
            *(bf16x8*)(&Kb[nxt][c1i >> 3][(c1i & 7) * 8]) = gK1;
            *(bf16x8*)(&Vb[nxt][c0i >> 3][(c0i & 7) * 8]) = gV0;
            *(bf16x8*)(&Vb[nxt][c1i >> 3][(c1i & 7) * 8]) = gV1;
            __syncthreads();
        }
    }

#pragma unroll
    for (int qi = 0; qi < 2; ++qi) {
        const float inv = 1.0f / lI[qi];
        const int qrow_idx = q0 + qi * 16 + l16;
#pragma unroll
        for (int mi = 0; mi < 4; ++mi) {
            f32x4 ov = o[mi][qi];
            s16x4 pkk = {(short)f2bf(ov.x * inv), (short)f2bf(ov.y * inv),
                         (short)f2bf(ov.z * inv), (short)f2bf(ov.w * inv)};
            int d0 = mi * 16 + quad * 4;
            *(s16x4*)(attnb + ((size_t)(b * N_ + qrow_idx)) * E_ + h * 64 + d0) = pkk;
        }
    }
}

// ---------------------------------------------------------------------------
// out = attn(bf16) @ Wo^T(bf16), fp32 out. grid (32,16), block 256.
// Wave: 32 token rows x 64 out-cols.  XCD swizzle groups same-row-block
// blocks per XCD: attnb slice (1 MB) + wob (2 MB) fit in 4 MB L2.
// ---------------------------------------------------------------------------
__global__ __launch_bounds__(256, 4)
void out_gemm_kernel(const unsigned short* __restrict__ attnb,
                     const unsigned short* __restrict__ wob,
                     float* __restrict__ out) {
    const int lane = threadIdx.x & 63;
    const int wave = threadIdx.x >> 6;
    const int l16  = lane & 15;
    const int quad = lane >> 4;

    const int flat = blockIdx.y * gridDim.x + blockIdx.x;    // 0..511
    const int t0b  = ((flat & 7) << 2) | ((flat >> 3) & 3);  // 0..31
    const int c0b  = flat >> 5;                              // 0..15
    const int t0 = t0b * 128 + wave * 32;
    const int c0 = c0b * 64;

    f32x4 acc[2][4];
#pragma unroll
    for (int mi = 0; mi < 2; ++mi)
#pragma unroll
        for (int t4 = 0; t4 < 4; ++t4) acc[mi][t4] = (f32x4){0.f, 0.f, 0.f, 0.f};

#pragma unroll 2
    for (int kc = 0; kc < E_ / 32; ++kc) {
        bf16x8 a[2], bb[4];
#pragma unroll
        for (int mi = 0; mi < 2; ++mi)
            a[mi] = *(const bf16x8*)(attnb + (size_t)(t0 + mi * 16 + l16) * E_ +
                                     kc * 32 + quad * 8);
#pragma unroll
        for (int t4 = 0; t4 < 4; ++t4)
            bb[t4] = *(const bf16x8*)(wob + (size_t)(c0 + t4 * 16 + l16) * E_ +
                                      kc * 32 + quad * 8);
#pragma unroll
        for (int mi = 0; mi < 2; ++mi)
#pragma unroll
            for (int t4 = 0; t4 < 4; ++t4)
                acc[mi][t4] = MFMA(a[mi], bb[t4], acc[mi][t4]);
    }

#pragma unroll
    for (int mi = 0; mi < 2; ++mi)
#pragma unroll
        for (int t4 = 0; t4 < 4; ++t4)
#pragma unroll
            for (int r = 0; r < 4; ++r)
                out[(size_t)(t0 + mi * 16 + quad * 4 + r) * E_ + c0 + t4 * 16 + l16] =
                    acc[mi][t4][r];
}

// ---------------------------------------------------------------------------
extern "C" void kernel_launch(void* const* d_in, const int* in_sizes, int n_in,
                              void* d_out, int out_size, void* d_ws, size_t ws_size,
                              hipStream_t stream) {
    const float* q    = (const float*)d_in[0];
    const float* k    = (const float*)d_in[1];
    const float* v    = (const float*)d_in[2];
    const int*   mask = (const int*)d_in[3];
    const float* Wq   = (const float*)d_in[4];
    const float* Wk   = (const float*)d_in[5];
    const float* Wv   = (const float*)d_in[6];
    const float* Wo   = (const float*)d_in[7];
    float* out = (float*)d_out;

    char* ws = (char*)d_ws;
    unsigned short* qh    = (unsigned short*)(ws);
    unsigned short* kh    = (unsigned short*)(ws + (size_t)8 * 1024 * 1024);
    unsigned short* vt    = (unsigned short*)(ws + (size_t)16 * 1024 * 1024);
    unsigned short* attnb = (unsigned short*)(ws + (size_t)24 * 1024 * 1024);
    // wob aliases qh's region: cvt_wo runs AFTER attn is done reading qh.
    unsigned short* wob   = (unsigned short*)(ws);

    dim3 blk(256);
    proj_kernel<<<dim3(N_ / 64, BH_, 3), blk, 0, stream>>>(q, k, v, Wq, Wk, Wv, qh, kh, vt);
    attn_kernel<<<dim3(16, 32), blk, 0, stream>>>(qh, kh, vt, mask, attnb);
    cvt_wo_kernel<<<dim3(E_ * E_ / 1024), blk, 0, stream>>>(Wo, wob);
    out_gemm_kernel<<<dim3(32, 16), blk, 0, stream>>>(attnb, wob, out);
}

// Round 5
// 224.152 us; speedup vs baseline: 1.9051x; 1.0788x over previous
//
#include <hip/hip_runtime.h>
#include <hip/hip_bf16.h>

#define B_ 2
#define N_ 2048
#define E_ 1024
#define H_ 16
#define D_ 64
#define BH_ (B_ * H_)

typedef __attribute__((ext_vector_type(4))) float f32x4;
typedef __attribute__((ext_vector_type(8))) short bf16x8;
typedef __attribute__((ext_vector_type(4))) short s16x4;
typedef __attribute__((ext_vector_type(4))) int i32x4;

#define MFMA(a, b, c) __builtin_amdgcn_mfma_f32_16x16x32_bf16(a, b, c, 0, 0, 0)

#define AS1(p) ((const __attribute__((address_space(1))) unsigned int*)(p))
#define AS3(p) ((__attribute__((address_space(3))) unsigned int*)(p))

static __device__ __forceinline__ unsigned short f2bf(float f) {
    unsigned int u = __builtin_bit_cast(unsigned int, f);
    u += 0x7fff + ((u >> 16) & 1);   // RNE; inputs are finite
    return (unsigned short)(u >> 16);
}
static __device__ __forceinline__ float bf2f(unsigned short s) {
    unsigned int u = ((unsigned int)s) << 16;
    return __builtin_bit_cast(float, u);
}
static __device__ __forceinline__ int pack2bf(float lo, float hi) {
    return (int)f2bf(lo) | ((int)f2bf(hi) << 16);
}
static __device__ __forceinline__ bf16x8 cvt8s(const float* __restrict__ p, float sc) {
    f32x4 a = *(const f32x4*)p;
    f32x4 b = *(const f32x4*)(p + 4);
    bf16x8 r;
    r[0] = (short)f2bf(a.x * sc); r[1] = (short)f2bf(a.y * sc);
    r[2] = (short)f2bf(a.z * sc); r[3] = (short)f2bf(a.w * sc);
    r[4] = (short)f2bf(b.x * sc); r[5] = (short)f2bf(b.y * sc);
    r[6] = (short)f2bf(b.z * sc); r[7] = (short)f2bf(b.w * sc);
    return r;
}

// ---------------------------------------------------------------------------
// Fused projections: z=0 -> qh = (q@Wq^T)*log2e/32, masked rows zeroed,
// layout [bh][n][d]; z=1 -> kh [bh][n][d]; z=2 -> vt [bh][d][n].
// All modes: D = W x X^T (m=dout, n=token) so [n][d] stores are 8-B vectors.
// grid (N/64, BH, 3), block 256.
// ---------------------------------------------------------------------------
__global__ __launch_bounds__(256, 4)
void proj_kernel(const float* __restrict__ q, const float* __restrict__ k,
                 const float* __restrict__ v,
                 const float* __restrict__ Wq, const float* __restrict__ Wk,
                 const float* __restrict__ Wv,
                 const int* __restrict__ mask,
                 unsigned short* __restrict__ qh, unsigned short* __restrict__ kh,
                 unsigned short* __restrict__ vt) {
    const int z = blockIdx.z;
    const float* X = (z == 0) ? q : (z == 1) ? k : v;
    const float* W = (z == 0) ? Wq : (z == 1) ? Wk : Wv;
    unsigned short* out = (z == 0) ? qh : (z == 1) ? kh : vt;
    const float wscale = (z == 0) ? (1.44269504f * 0.03125f) : 1.0f;

    const int lane = threadIdx.x & 63;
    const int wave = threadIdx.x >> 6;
    const int l16  = lane & 15;
    const int quad = lane >> 4;
    const int bh = blockIdx.y;
    const int b = bh >> 4, h = bh & 15;
    const int n0 = blockIdx.x * 64;
    const int tok = n0 + wave * 16 + l16;

    // X fragment: B-operand (lane l16 = token, quad*8 = k)
    const float* xrow = X + ((size_t)(b * N_ + tok)) * E_ + h * 64;
    bf16x8 xf[2];
    xf[0] = cvt8s(xrow + quad * 8, 1.0f);
    xf[1] = cvt8s(xrow + 32 + quad * 8, 1.0f);

    // W fragments: A-operand (lane l16 = dout row, quad*8 = k)
    const float* Wh = W + (size_t)h * 64 * 64;
    bf16x8 wf[4][2];
#pragma unroll
    for (int t4 = 0; t4 < 4; ++t4) {
        const float* wrow = Wh + (t4 * 16 + l16) * 64;
        wf[t4][0] = cvt8s(wrow + quad * 8, wscale);
        wf[t4][1] = cvt8s(wrow + 32 + quad * 8, wscale);
    }

    const int mk = (z == 0) ? mask[b * N_ + tok] : 1;

#pragma unroll
    for (int mi = 0; mi < 4; ++mi) {
        f32x4 a = {0.f, 0.f, 0.f, 0.f};
        a = MFMA(wf[mi][0], xf[0], a);   // D: row = dout (mi*16+quad*4+r), col = token (l16)
        a = MFMA(wf[mi][1], xf[1], a);
        if (z != 2) {
            s16x4 pk = {(short)f2bf(a.x), (short)f2bf(a.y),
                        (short)f2bf(a.z), (short)f2bf(a.w)};
            if (!mk) pk = (s16x4){0, 0, 0, 0};
            *(s16x4*)(out + ((size_t)bh * N_ + tok) * 64 + mi * 16 + quad * 4) = pk;
        } else {
#pragma unroll
            for (int r = 0; r < 4; ++r) {
                int dout = mi * 16 + quad * 4 + r;
                out[((size_t)bh * 64 + dout) * N_ + tok] = (unsigned short)f2bf(a[r]);
            }
        }
    }
}

// ---------------------------------------------------------------------------
__global__ __launch_bounds__(256)
void cvt_wo_kernel(const float* __restrict__ wo, unsigned short* __restrict__ wob) {
    int idx = blockIdx.x * 256 + threadIdx.x;
    f32x4 v = *(const f32x4*)(wo + (size_t)idx * 4);
    s16x4 r = {(short)f2bf(v.x), (short)f2bf(v.y), (short)f2bf(v.z), (short)f2bf(v.w)};
    *(s16x4*)(wob + (size_t)idx * 4) = r;
}

// ---------------------------------------------------------------------------
// Flash attention (validated round-4 structure). qh is pre-scaled+masked at
// proj time, so Q frags are plain loads.  K/V LDS double-buffered, XCD
// swizzle, shuffle-based P transform, no-max softmax.
// ---------------------------------------------------------------------------
__global__ __launch_bounds__(256, 2)
void attn_kernel(const unsigned short* __restrict__ qh,
                 const unsigned short* __restrict__ kh,
                 const unsigned short* __restrict__ vt,
                 unsigned short* __restrict__ attnb) {
    __shared__ short Kb[2][64][72];
    __shared__ short Vb[2][64][72];

    const int tid  = threadIdx.x;
    const int lane = tid & 63;
    const int wave = tid >> 6;
    const int l16  = lane & 15;
    const int quad = lane >> 4;

    const int flat = blockIdx.y * gridDim.x + blockIdx.x;   // 0..511
    const int qblk = flat >> 5;
    const int rem  = flat & 31;
    const int bh   = ((rem & 7) << 2) | (rem >> 3);
    const int b = bh >> 4, h = bh & 15;
    const int q0 = qblk * 128 + wave * 32;

    const unsigned short* kbase = kh + (size_t)bh * N_ * 64;
    const unsigned short* vbase = vt + (size_t)bh * 64 * N_;

    const int c0i = tid;
    const int c1i = tid + 256;

    const int srcA = (((quad * 2) & 3) << 4) + l16;
    const int srcB = (((quad * 2 + 1) & 3) << 4) + l16;
    const bool hiSel = (quad >= 2);

    // Q fragments (B-operand) — already scaled/masked
    bf16x8 qf[2][2];
#pragma unroll
    for (int qi = 0; qi < 2; ++qi) {
        const unsigned short* qrow = qh + ((size_t)bh * N_ + q0 + qi * 16 + l16) * 64;
        qf[qi][0] = *(const bf16x8*)(qrow + quad * 8);
        qf[qi][1] = *(const bf16x8*)(qrow + 32 + quad * 8);
    }

    float lI[2] = {0.f, 0.f};
    f32x4 o[4][2];
#pragma unroll
    for (int mi = 0; mi < 4; ++mi)
#pragma unroll
        for (int qi = 0; qi < 2; ++qi) o[mi][qi] = (f32x4){0.f, 0.f, 0.f, 0.f};

    bf16x8 gK0, gK1, gV0, gV1;
    gK0 = *(const bf16x8*)(kbase + c0i * 8);
    gK1 = *(const bf16x8*)(kbase + c1i * 8);
    gV0 = *(const bf16x8*)(vbase + (size_t)(c0i >> 3) * N_ + (c0i & 7) * 8);
    gV1 = *(const bf16x8*)(vbase + (size_t)(c1i >> 3) * N_ + (c1i & 7) * 8);
    *(bf16x8*)(&Kb[0][c0i >> 3][(c0i & 7) * 8]) = gK0;
    *(bf16x8*)(&Kb[0][c1i >> 3][(c1i & 7) * 8]) = gK1;
    *(bf16x8*)(&Vb[0][c0i >> 3][(c0i & 7) * 8]) = gV0;
    *(bf16x8*)(&Vb[0][c1i >> 3][(c1i & 7) * 8]) = gV1;
    __syncthreads();

    for (int kt = 0; kt < N_ / 64; ++kt) {
        const int cur = kt & 1;

        if (kt + 1 < N_ / 64) {
            const int k0n = (kt + 1) * 64;
            gK0 = *(const bf16x8*)(kbase + (size_t)k0n * 64 + c0i * 8);
            gK1 = *(const bf16x8*)(kbase + (size_t)k0n * 64 + c1i * 8);
            gV0 = *(const bf16x8*)(vbase + (size_t)(c0i >> 3) * N_ + k0n + (c0i & 7) * 8);
            gV1 = *(const bf16x8*)(vbase + (size_t)(c1i >> 3) * N_ + k0n + (c1i & 7) * 8);
        }

        bf16x8 ka[4][2];
#pragma unroll
        for (int t4 = 0; t4 < 4; ++t4) {
            ka[t4][0] = *(const bf16x8*)(&Kb[cur][t4 * 16 + l16][quad * 8]);
            ka[t4][1] = *(const bf16x8*)(&Kb[cur][t4 * 16 + l16][32 + quad * 8]);
        }

        f32x4 s[2][4];
#pragma unroll
        for (int qi = 0; qi < 2; ++qi)
#pragma unroll
            for (int t4 = 0; t4 < 4; ++t4) {
                f32x4 z = {0.f, 0.f, 0.f, 0.f};
                z = MFMA(ka[t4][0], qf[qi][0], z);
                z = MFMA(ka[t4][1], qf[qi][1], z);
                s[qi][t4] = z;
            }

        bf16x8 va[4][2];
#pragma unroll
        for (int mi = 0; mi < 4; ++mi) {
            va[mi][0] = *(const bf16x8*)(&Vb[cur][mi * 16 + l16][quad * 8]);
            va[mi][1] = *(const bf16x8*)(&Vb[cur][mi * 16 + l16][32 + quad * 8]);
        }

#pragma unroll
        for (int qi = 0; qi < 2; ++qi) {
            float rsum = 0.f;
            int pk[4][2];
#pragma unroll
            for (int t4 = 0; t4 < 4; ++t4) {
                f32x4 p;
#pragma unroll
                for (int r = 0; r < 4; ++r) {
                    p[r] = __builtin_amdgcn_exp2f(s[qi][t4][r]);
                    rsum += p[r];
                }
                pk[t4][0] = pack2bf(p.x, p.y);
                pk[t4][1] = pack2bf(p.z, p.w);
            }
            rsum += __shfl_xor(rsum, 16);
            rsum += __shfl_xor(rsum, 32);
            lI[qi] += rsum;

            i32x4 w0, w1;
#pragma unroll
            for (int d = 0; d < 2; ++d) {
                int a0 = __shfl(pk[0][d], srcA), a1 = __shfl(pk[1][d], srcA);
                int b0 = __shfl(pk[0][d], srcB), b1 = __shfl(pk[1][d], srcB);
                w0[d]     = hiSel ? a1 : a0;
                w0[2 + d] = hiSel ? b1 : b0;
                int c0 = __shfl(pk[2][d], srcA), c1 = __shfl(pk[3][d], srcA);
                int e0 = __shfl(pk[2][d], srcB), e1 = __shfl(pk[3][d], srcB);
                w1[d]     = hiSel ? c1 : c0;
                w1[2 + d] = hiSel ? e1 : e0;
            }
            bf16x8 pb0 = __builtin_bit_cast(bf16x8, w0);
            bf16x8 pb1 = __builtin_bit_cast(bf16x8, w1);

#pragma unroll
            for (int mi = 0; mi < 4; ++mi) {
                o[mi][qi] = MFMA(va[mi][0], pb0, o[mi][qi]);
                o[mi][qi] = MFMA(va[mi][1], pb1, o[mi][qi]);
            }
        }

        if (kt + 1 < N_ / 64) {
            const int nxt = cur ^ 1;
            *(bf16x8*)(&Kb[nxt][c0i >> 3][(c0i & 7) * 8]) = gK0;
            *(bf16x8*)(&Kb[nxt][c1i >> 3][(c1i & 7) * 8]) = gK1;
            *(bf16x8*)(&Vb[nxt][c0i >> 3][(c0i & 7) * 8]) = gV0;
            *(bf16x8*)(&Vb[nxt][c1i >> 3][(c1i & 7) * 8]) = gV1;
            __syncthreads();
        }
    }

#pragma unroll
    for (int qi = 0; qi < 2; ++qi) {
        const float inv = 1.0f / lI[qi];
        const int qrow_idx = q0 + qi * 16 + l16;
#pragma unroll
        for (int mi = 0; mi < 4; ++mi) {
            f32x4 ov = o[mi][qi];
            s16x4 pkk = {(short)f2bf(ov.x * inv), (short)f2bf(ov.y * inv),
                         (short)f2bf(ov.z * inv), (short)f2bf(ov.w * inv)};
            int d0 = mi * 16 + quad * 4;
            *(s16x4*)(attnb + ((size_t)(b * N_ + qrow_idx)) * E_ + h * 64 + d0) = pkk;
        }
    }
}

// ---------------------------------------------------------------------------
// out = attnb(4096x1024 bf16) @ wob^T(1024x1024 bf16) -> fp32.
// m97-style: 128x128 tile, BK=32, global_load_lds width 16, double-buffered
// LDS (c-major chunk layout: phys chunk = c*128 + r), 1 barrier/iter.
// grid (32, 8) = 256 blocks, 256 thr = 2x2 waves, wave = 64x64 (4x4 MFMA).
// ---------------------------------------------------------------------------
__global__ __launch_bounds__(256, 2)
void out_gemm_kernel(const unsigned short* __restrict__ A,
                     const unsigned short* __restrict__ Bw,
                     float* __restrict__ out) {
    __shared__ short As[2][128 * 32];   // 8 KB each
    __shared__ short Bs[2][128 * 32];

    const int tid  = threadIdx.x;
    const int lane = tid & 63;
    const int wave = tid >> 6;
    const int l16  = lane & 15;
    const int quad = lane >> 4;
    const int wm = wave & 1, wn = wave >> 1;
    const int m0 = blockIdx.x * 128;
    const int n0 = blockIdx.y * 128;

    const unsigned short* gA = A + (size_t)m0 * E_;
    const unsigned short* gB = Bw + (size_t)n0 * E_;

    f32x4 acc[4][4];
#pragma unroll
    for (int mt = 0; mt < 4; ++mt)
#pragma unroll
        for (int nt = 0; nt < 4; ++nt) acc[mt][nt] = (f32x4){0.f, 0.f, 0.f, 0.f};

    // chunk p = c*128 + r  (c = k-chunk 0..3, r = row 0..127); lane handles
    // p = j*256 + wave*64 + lane; LDS dest = wave-uniform base + lane*16.
#define OG_STAGE(buf, k0)                                                        \
    {                                                                            \
        _Pragma("unroll")                                                        \
        for (int j = 0; j < 2; ++j) {                                            \
            const int p = j * 256 + wave * 64 + lane;                            \
            const int c = p >> 7, r = p & 127;                                   \
            const int lb = (j * 256 + wave * 64) * 8;                            \
            __builtin_amdgcn_global_load_lds(                                    \
                AS1(gA + (size_t)r * E_ + (k0) + c * 8),                         \
                AS3(&As[buf][lb]), 16, 0, 0);                                    \
            __builtin_amdgcn_global_load_lds(                                    \
                AS1(gB + (size_t)r * E_ + (k0) + c * 8),                         \
                AS3(&Bs[buf][lb]), 16, 0, 0);                                    \
        }                                                                        \
    }

    OG_STAGE(0, 0)
    __syncthreads();

    for (int kt = 0; kt < E_ / 32; ++kt) {
        const int cur = kt & 1;
        if (kt + 1 < E_ / 32) OG_STAGE(cur ^ 1, (kt + 1) * 32)

        bf16x8 af[4], bf[4];
#pragma unroll
        for (int mt = 0; mt < 4; ++mt)
            af[mt] = *(const bf16x8*)(&As[cur][(quad * 128 + wm * 64 + mt * 16 + l16) * 8]);
#pragma unroll
        for (int nt = 0; nt < 4; ++nt)
            bf[nt] = *(const bf16x8*)(&Bs[cur][(quad * 128 + wn * 64 + nt * 16 + l16) * 8]);

#pragma unroll
        for (int mt = 0; mt < 4; ++mt)
#pragma unroll
            for (int nt = 0; nt < 4; ++nt)
                acc[mt][nt] = MFMA(af[mt], bf[nt], acc[mt][nt]);

        __syncthreads();   // drains prefetch vmcnt + guards next overwrite
    }

#pragma unroll
    for (int mt = 0; mt < 4; ++mt)
#pragma unroll
        for (int nt = 0; nt < 4; ++nt)
#pragma unroll
            for (int r = 0; r < 4; ++r)
                out[(size_t)(m0 + wm * 64 + mt * 16 + quad * 4 + r) * E_ +
                    n0 + wn * 64 + nt * 16 + l16] = acc[mt][nt][r];
#undef OG_STAGE
}

// ---------------------------------------------------------------------------
extern "C" void kernel_launch(void* const* d_in, const int* in_sizes, int n_in,
                              void* d_out, int out_size, void* d_ws, size_t ws_size,
                              hipStream_t stream) {
    const float* q    = (const float*)d_in[0];
    const float* k    = (const float*)d_in[1];
    const float* v    = (const float*)d_in[2];
    const int*   mask = (const int*)d_in[3];
    const float* Wq   = (const float*)d_in[4];
    const float* Wk   = (const float*)d_in[5];
    const float* Wv   = (const float*)d_in[6];
    const float* Wo   = (const float*)d_in[7];
    float* out = (float*)d_out;

    char* ws = (char*)d_ws;
    unsigned short* qh    = (unsigned short*)(ws);
    unsigned short* kh    = (unsigned short*)(ws + (size_t)8 * 1024 * 1024);
    unsigned short* vt    = (unsigned short*)(ws + (size_t)16 * 1024 * 1024);
    unsigned short* attnb = (unsigned short*)(ws + (size_t)24 * 1024 * 1024);
    // wob aliases qh's region: cvt_wo runs AFTER attn is done reading qh.
    unsigned short* wob   = (unsigned short*)(ws);

    dim3 blk(256);
    proj_kernel<<<dim3(N_ / 64, BH_, 3), blk, 0, stream>>>(q, k, v, Wq, Wk, Wv, mask,
                                                           qh, kh, vt);
    attn_kernel<<<dim3(16, 32), blk, 0, stream>>>(qh, kh, vt, attnb);
    cvt_wo_kernel<<<dim3(E_ * E_ / 1024), blk, 0, stream>>>(Wo, wob);
    out_gemm_kernel<<<dim3(32, 8), blk, 0, stream>>>(attnb, wob, out);
}